// Round 1
// baseline (1654.193 us; speedup 1.0000x reference)
//
#include <hip/hip_runtime.h>
#include <math.h>

// ---------------------------------------------------------------------------
// GTAN2: x = relu(x@fc1W.T+b); 10 hops of {x_new = x@W.T+b; h = h@W.T+b;
// attention edge weights w1=exp(lrelu(x1[s]+h1[t])), self weight w2;
// h = elu((seg_sum(w1*h[t], s) + w2*x_new) / (seg_sum(w1,s)+w2))}; out=h@fc2W.T+b
// Strategy: CSR by s (built per call), fp32 tiled GEMM with fused row-dots,
// per-node gather aggregation.
// ---------------------------------------------------------------------------

__device__ __forceinline__ float lrelu02(float v) { return v > 0.f ? v : 0.2f * v; }

__global__ __launch_bounds__(256) void k_count(const int* __restrict__ s, int* __restrict__ cnt, int E) {
    int e = blockIdx.x * 256 + threadIdx.x;
    if (e < E) atomicAdd(&cnt[s[e]], 1);
}

__global__ __launch_bounds__(1024) void k_scan(const int* __restrict__ cnt, int* __restrict__ rp, int N, int E) {
    __shared__ int part[1024];
    int tid = threadIdx.x;
    int chunk = (N + 1023) >> 10;
    int start = tid * chunk;
    int end = start + chunk; if (end > N) end = N;
    int sum = 0;
    for (int i = start; i < end; ++i) sum += cnt[i];
    part[tid] = sum;
    __syncthreads();
    for (int off = 1; off < 1024; off <<= 1) {
        int o = (tid >= off) ? part[tid - off] : 0;
        __syncthreads();
        part[tid] += o;
        __syncthreads();
    }
    int run = part[tid] - sum;  // exclusive prefix of this thread's chunk
    for (int i = start; i < end; ++i) { rp[i] = run; run += cnt[i]; }
    if (tid == 0) rp[N] = E;
}

__global__ __launch_bounds__(256) void k_scatter(const int* __restrict__ s, const int* __restrict__ t,
                                                 const int* __restrict__ rp, int* __restrict__ cursor,
                                                 int* __restrict__ t_sorted, int* __restrict__ s_sorted, int E) {
    int e = blockIdx.x * 256 + threadIdx.x;
    if (e < E) {
        int u = s[e];
        int pos = atomicAdd(&cursor[u], 1);
        int idx = rp[u] + pos;
        t_sorted[idx] = t[e];
        s_sorted[idx] = u;
    }
}

// Y[N, ldy] (cols c0..c0+63) = X[N,K] @ W[OUT,K]^T + bias, optional relu,
// optional fused per-row dots with dvA/dvB accumulated atomically into accA/accB.
__global__ __launch_bounds__(256) void k_gemm(
    const float* __restrict__ X, const float* __restrict__ W,
    const float* __restrict__ bias, float* __restrict__ Y,
    int N, int K, int ldy, int relu,
    const float* __restrict__ dvA, const float* __restrict__ dvB,
    float* __restrict__ accA, float* __restrict__ accB) {
    __shared__ float xs[16][68];  // [k][row], pad 68: 16B-aligned rows, bank-spread
    __shared__ float ws[16][68];  // [k][col]
    const int tid = threadIdx.x;
    const int r0 = blockIdx.x * 64;
    const int c0 = blockIdx.y * 64;
    const int tx = tid & 15, ty = tid >> 4;
    const int lr = tid >> 2;          // 0..63
    const int lk = (tid & 3) << 2;    // 0,4,8,12

    float acc[4][4] = {};
    for (int kb = 0; kb < K; kb += 16) {
        int rr = r0 + lr;
        float4 xv = make_float4(0.f, 0.f, 0.f, 0.f);
        if (rr < N) xv = *(const float4*)(X + (size_t)rr * K + kb + lk);
        float4 wv = *(const float4*)(W + (size_t)(c0 + lr) * K + kb + lk);
        __syncthreads();
        xs[lk + 0][lr] = xv.x; xs[lk + 1][lr] = xv.y; xs[lk + 2][lr] = xv.z; xs[lk + 3][lr] = xv.w;
        ws[lk + 0][lr] = wv.x; ws[lk + 1][lr] = wv.y; ws[lk + 2][lr] = wv.z; ws[lk + 3][lr] = wv.w;
        __syncthreads();
#pragma unroll
        for (int k = 0; k < 16; ++k) {
            const float4 a = *(const float4*)&xs[k][ty << 2];
            const float4 b = *(const float4*)&ws[k][tx << 2];
            acc[0][0] += a.x * b.x; acc[0][1] += a.x * b.y; acc[0][2] += a.x * b.z; acc[0][3] += a.x * b.w;
            acc[1][0] += a.y * b.x; acc[1][1] += a.y * b.y; acc[1][2] += a.y * b.z; acc[1][3] += a.y * b.w;
            acc[2][0] += a.z * b.x; acc[2][1] += a.z * b.y; acc[2][2] += a.z * b.z; acc[2][3] += a.z * b.w;
            acc[3][0] += a.w * b.x; acc[3][1] += a.w * b.y; acc[3][2] += a.w * b.z; acc[3][3] += a.w * b.w;
        }
    }

    const float4 bv = *(const float4*)(bias + c0 + (tx << 2));
    const bool doA = dvA != nullptr, doB = dvB != nullptr;
    float4 dA = make_float4(0.f, 0.f, 0.f, 0.f), dB = make_float4(0.f, 0.f, 0.f, 0.f);
    if (doA) dA = *(const float4*)(dvA + c0 + (tx << 2));
    if (doB) dB = *(const float4*)(dvB + c0 + (tx << 2));

#pragma unroll
    for (int ri = 0; ri < 4; ++ri) {
        int rr = r0 + (ty << 2) + ri;
        if (rr >= N) continue;  // uniform within each 16-lane tx group
        float4 v;
        v.x = acc[ri][0] + bv.x; v.y = acc[ri][1] + bv.y;
        v.z = acc[ri][2] + bv.z; v.w = acc[ri][3] + bv.w;
        float pA = v.x * dA.x + v.y * dA.y + v.z * dA.z + v.w * dA.w;
        float pB = v.x * dB.x + v.y * dB.y + v.z * dB.z + v.w * dB.w;
        if (relu) { v.x = fmaxf(v.x, 0.f); v.y = fmaxf(v.y, 0.f); v.z = fmaxf(v.z, 0.f); v.w = fmaxf(v.w, 0.f); }
        *(float4*)(Y + (size_t)rr * ldy + c0 + (tx << 2)) = v;
        if (doA || doB) {
#pragma unroll
            for (int m = 1; m < 16; m <<= 1) {
                pA += __shfl_xor(pA, m, 64);
                pB += __shfl_xor(pB, m, 64);
            }
            if (tx == 0) {
                if (doA) atomicAdd(&accA[rr], pA);
                if (doB) atomicAdd(&accB[rr], pB);
            }
        }
    }
}

__global__ __launch_bounds__(256) void k_w2(const float* __restrict__ x1a, const float* __restrict__ xa2a,
                                            float* __restrict__ w2v, int N) {
    int i = blockIdx.x * 256 + threadIdx.x;
    if (i < N) w2v[i] = expf(lrelu02(x1a[i] + xa2a[i]));
}

__global__ __launch_bounds__(256) void k_w1(const float* __restrict__ x1a, const float* __restrict__ h1a,
                                            const int* __restrict__ ss, const int* __restrict__ ts,
                                            float* __restrict__ w1s, int E) {
    int p = blockIdx.x * 256 + threadIdx.x;
    if (p < E) w1s[p] = expf(lrelu02(x1a[ss[p]] + h1a[ts[p]]));
}

// One wave per node u: h_out[u] = elu((sum_e w1_e*hlin[t_e] + w2*xnew[u]) / (sum_e w1_e + w2))
__global__ __launch_bounds__(64) void k_agg(const float* __restrict__ xnew, const float* __restrict__ hlin,
                                            const float* __restrict__ w2v, const float* __restrict__ w1s,
                                            const int* __restrict__ rp, const int* __restrict__ t_sorted,
                                            float* __restrict__ hout, int N) {
    int u = blockIdx.x;
    int l2 = threadIdx.x << 1;  // each lane: 2 consecutive floats of the 128
    float w2 = w2v[u];
    float2 xr = *(const float2*)(xnew + (size_t)u * 128 + l2);
    float accx = w2 * xr.x, accy = w2 * xr.y;
    float div = w2;
    int p = rp[u], pend = rp[u + 1];
    for (; p + 1 < pend; p += 2) {
        int t0 = t_sorted[p], t1 = t_sorted[p + 1];
        float w10 = w1s[p], w11 = w1s[p + 1];
        float2 h0 = *(const float2*)(hlin + (size_t)t0 * 128 + l2);
        float2 h1 = *(const float2*)(hlin + (size_t)t1 * 128 + l2);
        accx += w10 * h0.x; accy += w10 * h0.y;
        accx += w11 * h1.x; accy += w11 * h1.y;
        div += w10 + w11;
    }
    if (p < pend) {
        int t0 = t_sorted[p];
        float w10 = w1s[p];
        float2 h0 = *(const float2*)(hlin + (size_t)t0 * 128 + l2);
        accx += w10 * h0.x; accy += w10 * h0.y;
        div += w10;
    }
    float ox = accx / div, oy = accy / div;
    ox = ox > 0.f ? ox : expf(ox) - 1.f;
    oy = oy > 0.f ? oy : expf(oy) - 1.f;
    *(float2*)(hout + (size_t)u * 128 + l2) = make_float2(ox, oy);
}

extern "C" void kernel_launch(void* const* d_in, const int* in_sizes, int n_in,
                              void* d_out, int out_size, void* d_ws, size_t ws_size,
                              hipStream_t stream) {
    const float* x_in = (const float*)d_in[0];   // [N,256]
    const int*   s    = (const int*)d_in[1];     // [E]
    const int*   t    = (const int*)d_in[2];     // [E]
    const float* fc1W = (const float*)d_in[3];   // [128,256]
    const float* fc1b = (const float*)d_in[4];   // [128]
    const float* fcsW = (const float*)d_in[5];   // [10,128,128]
    const float* fcsb = (const float*)d_in[6];   // [10,128]
    const float* a1   = (const float*)d_in[7];   // [10,128]
    const float* a2   = (const float*)d_in[8];   // [10,128]
    const float* fc2W = (const float*)d_in[9];   // [64,128]
    const float* fc2b = (const float*)d_in[10];  // [64]

    const int N = in_sizes[0] / 256;  // 50000
    const int E = in_sizes[1];        // 800000

    char* ws = (char*)d_ws;
    size_t off = 0;
    auto alloc = [&](size_t bytes) -> void* {
        void* p = ws + off;
        off += (bytes + 255) & ~(size_t)255;
        return p;
    };
    float* xbuf  = (float*)alloc((size_t)N * 128 * 4);  // relu(fc1(x)), constant over hops
    float* bufA  = (float*)alloc((size_t)N * 128 * 4);  // hlin = h@W.T+b
    float* bufB  = (float*)alloc((size_t)N * 128 * 4);  // h state (agg output)
    float* xnew  = (float*)alloc((size_t)N * 128 * 4);
    float* acc3  = (float*)alloc((size_t)3 * N * 4);    // x1acc | xa2acc | h1acc
    float* x1acc = acc3, *xa2acc = acc3 + N, *h1acc = acc3 + 2 * N;
    float* w2v   = (float*)alloc((size_t)N * 4);
    float* w1s   = (float*)alloc((size_t)E * 4);
    int* row_ptr  = (int*)alloc((size_t)(N + 1) * 4);
    int* cnt      = (int*)alloc((size_t)N * 4);         // counts, then cursor
    int* t_sorted = (int*)alloc((size_t)E * 4);
    int* s_sorted = (int*)alloc((size_t)E * 4);

    // ---- CSR build (per call; graph-capture safe: only kernels + async memsets)
    hipMemsetAsync(cnt, 0, (size_t)N * 4, stream);
    k_count<<<(E + 255) / 256, 256, 0, stream>>>(s, cnt, E);
    k_scan<<<1, 1024, 0, stream>>>(cnt, row_ptr, N, E);
    hipMemsetAsync(cnt, 0, (size_t)N * 4, stream);
    k_scatter<<<(E + 255) / 256, 256, 0, stream>>>(s, t, row_ptr, cnt, t_sorted, s_sorted, E);

    // ---- fc1 + relu
    dim3 g1((N + 63) / 64, 2);
    k_gemm<<<g1, 256, 0, stream>>>(x_in, fc1W, fc1b, xbuf, N, 256, 128, 1,
                                   nullptr, nullptr, nullptr, nullptr);

    // ---- hops
    const float* hsrc = xbuf;
    for (int i = 0; i < 10; ++i) {
        const float* W   = fcsW + (size_t)i * 128 * 128;
        const float* b   = fcsb + (size_t)i * 128;
        const float* a1i = a1 + (size_t)i * 128;
        const float* a2i = a2 + (size_t)i * 128;
        hipMemsetAsync(acc3, 0, (size_t)3 * N * 4, stream);
        // x_new = x@W.T+b, fused x1 += x_new·a1, xa2 += x_new·a2
        k_gemm<<<g1, 256, 0, stream>>>(xbuf, W, b, xnew, N, 128, 128, 0,
                                       a1i, a2i, x1acc, xa2acc);
        // hlin = h@W.T+b, fused h1 += hlin·a2
        k_gemm<<<g1, 256, 0, stream>>>(hsrc, W, b, bufA, N, 128, 128, 0,
                                       a2i, nullptr, h1acc, nullptr);
        k_w2<<<(N + 255) / 256, 256, 0, stream>>>(x1acc, xa2acc, w2v, N);
        k_w1<<<(E + 255) / 256, 256, 0, stream>>>(x1acc, h1acc, s_sorted, t_sorted, w1s, E);
        k_agg<<<N, 64, 0, stream>>>(xnew, bufA, w2v, w1s, row_ptr, t_sorted, bufB, N);
        hsrc = bufB;
    }

    // ---- fc2
    dim3 g2((N + 63) / 64, 1);
    k_gemm<<<g2, 256, 0, stream>>>(bufB, fc2W, fc2b, (float*)d_out, N, 128, 64, 0,
                                   nullptr, nullptr, nullptr, nullptr);
}

// Round 2
// 1390.098 us; speedup vs baseline: 1.1900x; 1.1900x over previous
//
#include <hip/hip_runtime.h>
#include <math.h>

// ---------------------------------------------------------------------------
// GTAN2. R2: parallel scan; 128x128-tile GEMM (8x8 micro) with fused dual
// source (x & h share W) and direct-store row dots; w1/w2 fused into k_agg.
// ---------------------------------------------------------------------------

__device__ __forceinline__ float lrelu02(float v) { return v > 0.f ? v : 0.2f * v; }

// ---------------- CSR build ----------------
__global__ __launch_bounds__(256) void k_count(const int* __restrict__ s, int* __restrict__ cnt, int E) {
    int e = blockIdx.x * 256 + threadIdx.x;
    if (e < E) atomicAdd(&cnt[s[e]], 1);
}

__global__ __launch_bounds__(256) void k_scan1(const int* __restrict__ cnt, int* __restrict__ bs, int N) {
    __shared__ int sh[256];
    int idx = blockIdx.x * 256 + threadIdx.x;
    sh[threadIdx.x] = (idx < N) ? cnt[idx] : 0;
    __syncthreads();
#pragma unroll
    for (int off = 128; off; off >>= 1) {
        if (threadIdx.x < off) sh[threadIdx.x] += sh[threadIdx.x + off];
        __syncthreads();
    }
    if (threadIdx.x == 0) bs[blockIdx.x] = sh[0];
}

__global__ __launch_bounds__(256) void k_scan2(int* __restrict__ bs, int G) {
    __shared__ int sh[256];
    int t = threadIdx.x;
    int v = (t < G) ? bs[t] : 0;
    sh[t] = v;
    __syncthreads();
    int val = v;
#pragma unroll
    for (int off = 1; off < 256; off <<= 1) {
        int o = (t >= off) ? sh[t - off] : 0;
        __syncthreads();
        val += o; sh[t] = val;
        __syncthreads();
    }
    if (t < G) bs[t] = val - v;  // exclusive
}

__global__ __launch_bounds__(256) void k_scan3(const int* __restrict__ cnt, const int* __restrict__ bs,
                                               int* __restrict__ rp, int N) {
    __shared__ int sh[256];
    int t = threadIdx.x;
    int idx = blockIdx.x * 256 + t;
    int v = (idx < N) ? cnt[idx] : 0;
    sh[t] = v;
    __syncthreads();
    int val = v;
#pragma unroll
    for (int off = 1; off < 256; off <<= 1) {
        int o = (t >= off) ? sh[t - off] : 0;
        __syncthreads();
        val += o; sh[t] = val;
        __syncthreads();
    }
    if (idx <= N) rp[idx] = val - v + bs[blockIdx.x];
}

__global__ __launch_bounds__(256) void k_scatter(const int* __restrict__ s, const int* __restrict__ t,
                                                 const int* __restrict__ rp, int* __restrict__ cursor,
                                                 int* __restrict__ t_sorted, int E) {
    int e = blockIdx.x * 256 + threadIdx.x;
    if (e < E) {
        int u = s[e];
        int pos = atomicAdd(&cursor[u], 1);
        t_sorted[rp[u] + pos] = t[e];
    }
}

// ---------------- GEMM: Y = X @ W^T + b, 128x128 tile, 8x8 micro ----------------
// Dual-source: blocks [0,nblk0) use X0->Y0 (dots dA0->oA0, dB0->oB0),
// blocks [nblk0,..) use X1->Y1 (dot dA1->oA1). Dots are over post-bias,
// pre-activation values; direct store (tile spans all cols).
#define BK 32
#define LDSP 132

__global__ __launch_bounds__(256) void k_mm(
    const float* __restrict__ X0, const float* __restrict__ X1, int nblk0,
    const float* __restrict__ W, const float* __restrict__ bias,
    float* __restrict__ Y0, float* __restrict__ Y1,
    int N, int K, int ncols, int ldy, int relu,
    const float* __restrict__ dA0, float* __restrict__ oA0,
    const float* __restrict__ dB0, float* __restrict__ oB0,
    const float* __restrict__ dA1, float* __restrict__ oA1) {
    __shared__ float Xs[BK][LDSP];
    __shared__ float Ws[BK][LDSP];
    const int tid = threadIdx.x;
    const bool second = (int)blockIdx.x >= nblk0;
    const int bx = second ? blockIdx.x - nblk0 : blockIdx.x;
    const float* X = second ? X1 : X0;
    float* Y = second ? Y1 : Y0;
    const float* dA = second ? dA1 : dA0;
    float* oA = second ? oA1 : oA0;
    const float* dB = second ? nullptr : dB0;
    float* oB = second ? nullptr : oB0;
    const int r0 = bx * 128;
    const int tx = tid & 15, ty = tid >> 4;
    const int srow = tid >> 1;          // 0..127
    const int shalf = (tid & 1) << 4;   // 0 or 16

    float acc[8][8] = {};
    for (int kb = 0; kb < K; kb += BK) {
        int gr = r0 + srow;
        bool xok = gr < N;
        bool wok = srow < ncols;
        const float* xp = X + (size_t)gr * K + kb + shalf;
        const float* wp = W + (size_t)srow * K + kb + shalf;
        float4 xv[4], wv[4];
#pragma unroll
        for (int q = 0; q < 4; ++q) {
            xv[q] = xok ? *(const float4*)(xp + q * 4) : make_float4(0.f, 0.f, 0.f, 0.f);
            wv[q] = wok ? *(const float4*)(wp + q * 4) : make_float4(0.f, 0.f, 0.f, 0.f);
        }
        __syncthreads();
#pragma unroll
        for (int q = 0; q < 4; ++q) {
            Xs[shalf + q * 4 + 0][srow] = xv[q].x;
            Xs[shalf + q * 4 + 1][srow] = xv[q].y;
            Xs[shalf + q * 4 + 2][srow] = xv[q].z;
            Xs[shalf + q * 4 + 3][srow] = xv[q].w;
            Ws[shalf + q * 4 + 0][srow] = wv[q].x;
            Ws[shalf + q * 4 + 1][srow] = wv[q].y;
            Ws[shalf + q * 4 + 2][srow] = wv[q].z;
            Ws[shalf + q * 4 + 3][srow] = wv[q].w;
        }
        __syncthreads();
#pragma unroll 8
        for (int k = 0; k < BK; ++k) {
            const float4 a0 = *(const float4*)&Xs[k][ty * 8];
            const float4 a1 = *(const float4*)&Xs[k][ty * 8 + 4];
            const float4 b0 = *(const float4*)&Ws[k][tx * 4];
            const float4 b1 = *(const float4*)&Ws[k][tx * 4 + 64];
            const float av[8] = {a0.x, a0.y, a0.z, a0.w, a1.x, a1.y, a1.z, a1.w};
            const float bv[8] = {b0.x, b0.y, b0.z, b0.w, b1.x, b1.y, b1.z, b1.w};
#pragma unroll
            for (int i = 0; i < 8; ++i)
#pragma unroll
                for (int j = 0; j < 8; ++j)
                    acc[i][j] += av[i] * bv[j];
        }
    }

    const int cola = tx * 4, colb = 64 + tx * 4;
    const bool haveb = colb < ncols;
    const float4 bva = *(const float4*)(bias + cola);
    const float4 bvb = haveb ? *(const float4*)(bias + colb) : make_float4(0.f, 0.f, 0.f, 0.f);
    const bool doA = dA != nullptr, doB = dB != nullptr;
    float4 dAa = make_float4(0.f,0.f,0.f,0.f), dAb = dAa, dBa = dAa, dBb = dAa;
    if (doA) { dAa = *(const float4*)(dA + cola); dAb = *(const float4*)(dA + colb); }
    if (doB) { dBa = *(const float4*)(dB + cola); dBb = *(const float4*)(dB + colb); }

#pragma unroll
    for (int i = 0; i < 8; ++i) {
        int r = r0 + ty * 8 + i;
        if (r >= N) continue;  // uniform across tx-subgroup; shfl below stays safe
        float va[4], vb[4];
        va[0] = acc[i][0] + bva.x; va[1] = acc[i][1] + bva.y;
        va[2] = acc[i][2] + bva.z; va[3] = acc[i][3] + bva.w;
        vb[0] = acc[i][4] + bvb.x; vb[1] = acc[i][5] + bvb.y;
        vb[2] = acc[i][6] + bvb.z; vb[3] = acc[i][7] + bvb.w;
        float pA = 0.f, pB = 0.f;
        if (doA) {
            pA = va[0]*dAa.x + va[1]*dAa.y + va[2]*dAa.z + va[3]*dAa.w
               + vb[0]*dAb.x + vb[1]*dAb.y + vb[2]*dAb.z + vb[3]*dAb.w;
        }
        if (doB) {
            pB = va[0]*dBa.x + va[1]*dBa.y + va[2]*dBa.z + va[3]*dBa.w
               + vb[0]*dBb.x + vb[1]*dBb.y + vb[2]*dBb.z + vb[3]*dBb.w;
        }
        if (relu) {
#pragma unroll
            for (int j = 0; j < 4; ++j) { va[j] = fmaxf(va[j], 0.f); vb[j] = fmaxf(vb[j], 0.f); }
        }
        *(float4*)(Y + (size_t)r * ldy + cola) = make_float4(va[0], va[1], va[2], va[3]);
        if (haveb) *(float4*)(Y + (size_t)r * ldy + colb) = make_float4(vb[0], vb[1], vb[2], vb[3]);
        if (doA) {
#pragma unroll
            for (int m = 1; m < 16; m <<= 1) {
                pA += __shfl_xor(pA, m, 64);
                if (doB) pB += __shfl_xor(pB, m, 64);
            }
            if (tx == 0) {
                oA[r] = pA;
                if (doB) oB[r] = pB;
            }
        }
    }
}

// ---------------- aggregation: fused w1/w2 + gather + elu ----------------
// One wave per node u. Lanes cooperatively compute per-edge w1 (1 exp/edge,
// lane-distributed), broadcast via shfl while gathering 512B hlin rows.
__global__ __launch_bounds__(64) void k_agg(
    const float* __restrict__ xnew, const float* __restrict__ hlin,
    const float* __restrict__ x1a, const float* __restrict__ xa2a,
    const float* __restrict__ h1a, const int* __restrict__ rp,
    const int* __restrict__ ts, float* __restrict__ hout, int N) {
    int u = blockIdx.x;
    int lane = threadIdx.x;
    int l2 = lane << 1;
    float x1u = x1a[u];
    float w2 = expf(lrelu02(x1u + xa2a[u]));
    float2 xr = *(const float2*)(xnew + (size_t)u * 128 + l2);
    float accx = w2 * xr.x, accy = w2 * xr.y;
    float div = w2;
    int p0 = rp[u], p1 = rp[u + 1];
    for (int base = p0; base < p1; base += 64) {
        int e = base + lane;
        int tv = 0;
        float wv = 0.f;
        if (e < p1) {
            tv = ts[e];
            wv = expf(lrelu02(x1u + h1a[tv]));
        }
        int m = p1 - base; if (m > 64) m = 64;
        for (int j = 0; j < m; ++j) {
            float w = __shfl(wv, j, 64);
            int tt = __shfl(tv, j, 64);
            float2 hr = *(const float2*)(hlin + (size_t)tt * 128 + l2);
            accx += w * hr.x;
            accy += w * hr.y;
            div += w;
        }
    }
    float ox = accx / div, oy = accy / div;
    ox = ox > 0.f ? ox : expf(ox) - 1.f;
    oy = oy > 0.f ? oy : expf(oy) - 1.f;
    *(float2*)(hout + (size_t)u * 128 + l2) = make_float2(ox, oy);
}

// ---------------- launch ----------------
extern "C" void kernel_launch(void* const* d_in, const int* in_sizes, int n_in,
                              void* d_out, int out_size, void* d_ws, size_t ws_size,
                              hipStream_t stream) {
    const float* x_in = (const float*)d_in[0];
    const int*   s    = (const int*)d_in[1];
    const int*   t    = (const int*)d_in[2];
    const float* fc1W = (const float*)d_in[3];
    const float* fc1b = (const float*)d_in[4];
    const float* fcsW = (const float*)d_in[5];
    const float* fcsb = (const float*)d_in[6];
    const float* a1   = (const float*)d_in[7];
    const float* a2   = (const float*)d_in[8];
    const float* fc2W = (const float*)d_in[9];
    const float* fc2b = (const float*)d_in[10];

    const int N = in_sizes[0] / 256;  // 50000
    const int E = in_sizes[1];        // 800000
    const int G = (N + 255) / 256;    // 196 scan blocks
    const int NB = (N + 127) / 128;   // 391 gemm row-blocks

    char* ws = (char*)d_ws;
    size_t off = 0;
    auto alloc = [&](size_t bytes) -> void* {
        void* p = ws + off;
        off += (bytes + 255) & ~(size_t)255;
        return p;
    };
    float* xbuf  = (float*)alloc((size_t)N * 128 * 4);
    float* bufA  = (float*)alloc((size_t)N * 128 * 4);  // hlin
    float* bufB  = (float*)alloc((size_t)N * 128 * 4);  // h state
    float* xnew  = (float*)alloc((size_t)N * 128 * 4);
    float* x1a   = (float*)alloc((size_t)N * 4);
    float* xa2a  = (float*)alloc((size_t)N * 4);
    float* h1a   = (float*)alloc((size_t)N * 4);
    int* row_ptr  = (int*)alloc((size_t)(N + 1) * 4);
    int* cnt      = (int*)alloc((size_t)N * 4);
    int* bsums    = (int*)alloc((size_t)256 * 4);
    int* t_sorted = (int*)alloc((size_t)E * 4);

    // CSR build
    hipMemsetAsync(cnt, 0, (size_t)N * 4, stream);
    k_count<<<(E + 255) / 256, 256, 0, stream>>>(s, cnt, E);
    k_scan1<<<G, 256, 0, stream>>>(cnt, bsums, N);
    k_scan2<<<1, 256, 0, stream>>>(bsums, G);
    k_scan3<<<G, 256, 0, stream>>>(cnt, bsums, row_ptr, N);
    hipMemsetAsync(cnt, 0, (size_t)N * 4, stream);
    k_scatter<<<(E + 255) / 256, 256, 0, stream>>>(s, t, row_ptr, cnt, t_sorted, E);

    // fc1 + relu
    k_mm<<<NB, 256, 0, stream>>>(x_in, nullptr, NB, fc1W, fc1b, xbuf, nullptr,
                                 N, 256, 128, 128, 1,
                                 nullptr, nullptr, nullptr, nullptr, nullptr, nullptr);

    // hops
    const float* hsrc = xbuf;
    for (int i = 0; i < 10; ++i) {
        const float* W   = fcsW + (size_t)i * 128 * 128;
        const float* b   = fcsb + (size_t)i * 128;
        const float* a1i = a1 + (size_t)i * 128;
        const float* a2i = a2 + (size_t)i * 128;
        k_mm<<<2 * NB, 256, 0, stream>>>(xbuf, hsrc, NB, W, b, xnew, bufA,
                                         N, 128, 128, 128, 0,
                                         a1i, x1a, a2i, xa2a, a2i, h1a);
        k_agg<<<N, 64, 0, stream>>>(xnew, bufA, x1a, xa2a, h1a, row_ptr, t_sorted, bufB, N);
        hsrc = bufB;
    }

    // fc2
    k_mm<<<NB, 256, 0, stream>>>(bufB, nullptr, NB, fc2W, fc2b, (float*)d_out, nullptr,
                                 N, 128, 64, 64, 0,
                                 nullptr, nullptr, nullptr, nullptr, nullptr, nullptr);
}